// Round 9
// baseline (128.056 us; speedup 1.0000x reference)
//
#include <hip/hip_runtime.h>
#include <hip/hip_bf16.h>

#define BB 8
#define CC 16
#define EE 256
#define HH 256
#define WW 256
#define HPAD 258
#define WPAD 258
#define EMB_ROW (EE*9)

typedef __attribute__((ext_vector_type(8)))  __bf16 bf16x8;
typedef __attribute__((ext_vector_type(16))) float  f32x16;
typedef __attribute__((ext_vector_type(4)))  float  f32x4;

// ---- ws layout ----
#define XT_BYTES  17040384            // [BB][HPAD][WPAD][CC] bf16
#define WS_NEEDED (XT_BYTES + 589824) // + [BB][9][EE][CC] bf16

#define NX (BB*HPAD*WPAD)
#define NW (BB*9*EE*CC)
#define PREP_BLOCKS ((NX + NW + 255) / 256)

// ---------------- merged prep: x-transpose + weight gather ----------------
__global__ __launch_bounds__(256) void prep_all(const float* __restrict__ x,
                                                const int* __restrict__ indices,
                                                const float* __restrict__ emb,
                                                __hip_bfloat16* __restrict__ Xt,
                                                __hip_bfloat16* __restrict__ Wg) {
    const int t = blockIdx.x * 256 + threadIdx.x;
    if (t < NX) {
        const int wp = t % WPAD;
        const int r  = t / WPAD;
        const int hp = r % HPAD;
        const int b  = r / HPAD;
        union { __hip_bfloat16 v[16]; uint4 q[2]; } u;
        if (hp >= 1 && hp <= HH && wp >= 1 && wp <= WW) {
            const float* xp = x + (size_t)b * CC * HH * WW + (size_t)(hp - 1) * WW + (wp - 1);
            #pragma unroll
            for (int c = 0; c < CC; ++c)
                u.v[c] = __float2bfloat16(xp[(size_t)c * HH * WW]);
        } else {
            #pragma unroll
            for (int c = 0; c < CC; ++c) u.v[c] = __float2bfloat16(0.f);
        }
        uint4* dst = reinterpret_cast<uint4*>(Xt + (size_t)t * CC);
        dst[0] = u.q[0];
        dst[1] = u.q[1];
    } else if (t < NX + NW) {
        const int u  = t - NX;
        const int c  = u & 15;
        const int e  = (u >> 4) & 255;
        const int bt = u >> 12;
        const int tap = bt % 9;
        const int b   = bt / 9;
        Wg[u] = __float2bfloat16(emb[(size_t)indices[b * CC + c] * EMB_ROW + e * 9 + tap]);
    }
}

// ---------------- main: implicit-GEMM conv, h-streaming stores ----------------
// grid: (BB, 4, 8) = 256 blocks, exactly 1 per CU. Block = 32e x 256w x 64h.
// Per (block,e) the store stream is 64 consecutive 1KB rows = 64KB strictly
// sequential -> DRAM page-hit runs comparable to a fill kernel.
// Per h: MFMA 32e x 32w tile -> scatter lds[p] -> {lgkmcnt(0); s_barrier} ->
// read back contiguous 1KB (e,h) rows, nt-store (no vmcnt drain at barrier).
__global__ __launch_bounds__(512) void conv_mfma(
    const __bf16* __restrict__ Xt,      // [BB][HPAD][WPAD][CC]
    const __bf16* __restrict__ Wg,      // [BB][9][EE][CC]
    const float*  __restrict__ bias,    // [EE]
    float*        __restrict__ out)     // [BB][EE][HH][WW]
{
    __shared__ float lds[2][32 * 256];  // 2 x 32 KB

    const int b  = blockIdx.x;          // batch fastest -> XCD k handles batch k
    const int hc = blockIdx.y;          // h-chunk of 64 rows
    const int ez = blockIdx.z;          // e-tile of 32

    const int tid   = threadIdx.x;
    const int lane  = tid & 63;
    const int wid   = tid >> 6;         // 0..7
    const int l31   = lane & 31;
    const int lhalf = lane >> 5;

    const int e0 = ez * 32;
    const int w0 = wid * 32;
    const int h0 = hc * 64;

    // A fragments: 9 taps (identical across the 8 waves -> L1 broadcast)
    bf16x8 afrag[9];
    #pragma unroll
    for (int tap = 0; tap < 9; ++tap) {
        const __bf16* ap = Wg + ((size_t)(b * 9 + tap) * EE + (e0 + l31)) * CC + lhalf * 8;
        afrag[tap] = *reinterpret_cast<const bf16x8*>(ap);
    }

    // bias per C/D reg
    float bv[16];
    #pragma unroll
    for (int r = 0; r < 16; ++r) {
        const int erow = (r & 3) + 8 * (r >> 2) + 4 * lhalf;
        bv[r] = bias[e0 + erow];
    }

    int p = 0;
    for (int h = h0; h < h0 + 64; ++h, p ^= 1) {
        f32x16 acc;
        #pragma unroll
        for (int r = 0; r < 16; ++r) acc[r] = bv[r];

        #pragma unroll
        for (int kh = 0; kh < 3; ++kh) {
            const __bf16* bp = Xt + ((size_t)(b * HPAD + (h + kh)) * WPAD + w0 + l31) * CC + lhalf * 8;
            #pragma unroll
            for (int kw = 0; kw < 3; ++kw) {
                bf16x8 bfrag = *reinterpret_cast<const bf16x8*>(bp + kw * CC);
                acc = __builtin_amdgcn_mfma_f32_32x32x16_bf16(afrag[kh * 3 + kw], bfrag, acc, 0, 0, 0);
            }
        }

        // scatter acc into lds[p][erow][w]  (2-way bank alias only -> free)
        #pragma unroll
        for (int r = 0; r < 16; ++r) {
            const int erow = (r & 3) + 8 * (r >> 2) + 4 * lhalf;
            lds[p][erow * 256 + w0 + l31] = acc[r];
        }

        // barrier WITHOUT vmcnt drain: own DS ops done, then workgroup sync
        asm volatile("s_waitcnt lgkmcnt(0)" ::: "memory");
        __builtin_amdgcn_s_barrier();

        // coalesced store: wave wid stores e-rows wid*4 .. wid*4+3;
        // each instruction writes a full contiguous 1KB row; consecutive h
        // extend each e-row's stream sequentially (64KB runs).
        #pragma unroll
        for (int i = 0; i < 4; ++i) {
            const int e = wid * 4 + i;
            const f32x4 v = *reinterpret_cast<const f32x4*>(&lds[p][e * 256 + lane * 4]);
            __builtin_nontemporal_store(v,
                reinterpret_cast<f32x4*>(&out[((size_t)(b * EE + e0 + e) * HH + h) * WW + lane * 4]));
        }
    }
}

// ---------------- fallback: f32 direct conv (if ws too small) ----------------
#define EBLK 4
#define RBLK 4
__global__ __launch_bounds__(256) void conv_emb_f32(
    const float* __restrict__ x, const int* __restrict__ indices,
    const float* __restrict__ emb, const float* __restrict__ bias,
    float* __restrict__ out)
{
    const int w  = threadIdx.x;
    const int h0 = blockIdx.x * RBLK;
    const int e0 = blockIdx.y * EBLK;
    const int b  = blockIdx.z;

    float acc[RBLK][EBLK];
    #pragma unroll
    for (int r = 0; r < RBLK; ++r)
        #pragma unroll
        for (int e = 0; e < EBLK; ++e) acc[r][e] = 0.f;

    #pragma unroll 1
    for (int c = 0; c < CC; ++c) {
        const float* xp = x + (size_t)(b * CC + c) * HH * WW;
        float xv[RBLK + 2][3];
        #pragma unroll
        for (int ir = 0; ir < RBLK + 2; ++ir) {
            const int h = h0 + ir - 1;
            if (h >= 0 && h < HH) {
                const float* row = xp + (size_t)h * WW;
                xv[ir][1] = row[w];
                xv[ir][0] = (w > 0)      ? row[w - 1] : 0.f;
                xv[ir][2] = (w < WW - 1) ? row[w + 1] : 0.f;
            } else {
                xv[ir][0] = 0.f; xv[ir][1] = 0.f; xv[ir][2] = 0.f;
            }
        }
        const int idx = indices[b * CC + c];
        const float* wp = emb + (size_t)idx * EMB_ROW + e0 * 9;
        #pragma unroll
        for (int e = 0; e < EBLK; ++e)
            #pragma unroll
            for (int kh = 0; kh < 3; ++kh)
                #pragma unroll
                for (int kw = 0; kw < 3; ++kw) {
                    const float wv = wp[e * 9 + kh * 3 + kw];
                    #pragma unroll
                    for (int r = 0; r < RBLK; ++r)
                        acc[r][e] += xv[r + kh][kw] * wv;
                }
    }
    #pragma unroll
    for (int e = 0; e < EBLK; ++e) {
        const float bvv = bias[e0 + e];
        #pragma unroll
        for (int r = 0; r < RBLK; ++r)
            out[((size_t)(b * EE + e0 + e) * HH + (h0 + r)) * WW + w] = acc[r][e] + bvv;
    }
}

extern "C" void kernel_launch(void* const* d_in, const int* in_sizes, int n_in,
                              void* d_out, int out_size, void* d_ws, size_t ws_size,
                              hipStream_t stream) {
    const float* x       = (const float*)d_in[0];
    const int*   indices = (const int*)  d_in[1];
    const float* emb     = (const float*)d_in[2];
    const float* bias    = (const float*)d_in[3];
    float*       out     = (float*)d_out;

    if (ws_size < (size_t)WS_NEEDED) {
        dim3 grid(HH / RBLK, EE / EBLK, BB);
        conv_emb_f32<<<grid, dim3(256), 0, stream>>>(x, indices, emb, bias, out);
        return;
    }

    __hip_bfloat16* Xt = (__hip_bfloat16*)d_ws;
    __hip_bfloat16* Wg = (__hip_bfloat16*)((char*)d_ws + XT_BYTES);

    prep_all<<<dim3(PREP_BLOCKS), dim3(256), 0, stream>>>(x, indices, emb, Xt, Wg);

    conv_mfma<<<dim3(BB, 4, 8), dim3(512), 0, stream>>>(
        (const __bf16*)Xt, (const __bf16*)Wg, bias, out);
}

// Round 10
// 111.758 us; speedup vs baseline: 1.1458x; 1.1458x over previous
//
#include <hip/hip_runtime.h>
#include <hip/hip_bf16.h>

#define BB 8
#define CC 16
#define EE 256
#define HH 256
#define WW 256
#define EMB_ROW (EE*9)

typedef __attribute__((ext_vector_type(8)))  __bf16 bf16x8;
typedef __attribute__((ext_vector_type(16))) float  f32x16;
typedef __attribute__((ext_vector_type(4)))  float  f32x4;

// ---- LDS layout (bytes) ----
// W    : [9][32e][16c] bf16   @ 0       (9216 B)
// XRING: 4 slots x [258wp][16c] bf16 @ 9216, slot stride 8256 B
// EPI  : [32e][256w] f32      @ 42240   (32768 B)
#define LDS_X_OFF   9216
#define SLOT_BYTES  8256
#define LDS_EPI_OFF 42240
#define LDS_TOTAL   75008

#define NTASK 2064   // 8 c-pairs * 258 wp per staged row

__device__ __forceinline__ unsigned pack_bf2(float a, float b) {
    union { __hip_bfloat162 h; unsigned u; } t;
    t.h.x = __float2bfloat16(a);
    t.h.y = __float2bfloat16(b);
    return t.u;
}

// X-ring address swizzle: 32B cell per wp; XOR byte bit4 with wp bit2 so
// consecutive-wp b128 reads cover all 8 LDS granules (write & read agree).
__device__ __forceinline__ int xswz(int wp, int inner) {
    return ((wp << 5) | inner) ^ ((wp & 4) << 2);
}

// grid: (BB, 16, 8)  block: 512 (8 waves). Block = 32e x 256w x 16h.
__global__ __launch_bounds__(512, 4) void conv_fused(
    const float* __restrict__ x,        // [B][C][H][W] f32
    const int*   __restrict__ indices,  // [B][C]
    const float* __restrict__ emb,      // [64][E*9] f32
    const float* __restrict__ bias,     // [E]
    float*       __restrict__ out)      // [B][E][H][W] f32
{
    __shared__ __align__(16) char smem[LDS_TOTAL];
    char*  WB  = smem;
    char*  XB  = smem + LDS_X_OFF;
    float* EPI = (float*)(smem + LDS_EPI_OFF);

    const int b  = blockIdx.x;          // batch fastest -> XCD k handles batch k
    const int hc = blockIdx.y;          // 16 h-chunks of 16
    const int ez = blockIdx.z;          // 8 e-tiles of 32
    const int tid   = threadIdx.x;
    const int lane  = tid & 63;
    const int wid   = tid >> 6;         // 0..7
    const int l31   = lane & 31;
    const int lhalf = lane >> 5;
    const int e0 = ez * 32;
    const int w0 = wid * 32;
    const int h0 = hc * 16;

    // ---- W gather: thread (e = tid>>4, c = tid&15) pulls 9 contiguous taps
    {
        const int e = tid >> 4, c = tid & 15;
        const int idx = indices[b * CC + c];
        const float* wrow = emb + (size_t)idx * EMB_ROW + (size_t)(e0 + e) * 9;
        #pragma unroll
        for (int tap = 0; tap < 9; ++tap) {
            *reinterpret_cast<__hip_bfloat16*>(WB + tap * 1024 + e * 32 + c * 2) =
                __float2bfloat16(wrow[tap]);
        }
    }

    // ---- x staging: T14 split (issue loads early, ds_write late) ----
    float r0[5], r1[5];
    auto issue_loads = [&](int ir) {
        #pragma unroll
        for (int k = 0; k < 5; ++k) {
            const int u = tid + 512 * k;
            if (u < NTASK) {
                const int cp = u / 258;
                const int wp = u - cp * 258;
                const int iw = wp - 1;
                const bool v = ((unsigned)iw < 256u) && ((unsigned)ir < 256u);
                const float* p = x + (((size_t)(b * CC + 2 * cp) * HH + (ir & 255)) * WW + (iw & 255));
                r0[k] = v ? p[0] : 0.f;
                r1[k] = v ? p[HH * WW] : 0.f;
            }
        }
    };
    auto write_stage = [&](int ir) {
        const int slot = (ir + 1) & 3;
        #pragma unroll
        for (int k = 0; k < 5; ++k) {
            const int u = tid + 512 * k;
            if (u < NTASK) {
                const int cp = u / 258;
                const int wp = u - cp * 258;
                *reinterpret_cast<unsigned*>(XB + slot * SLOT_BYTES + xswz(wp, cp << 2)) =
                    pack_bf2(r0[k], r1[k]);
            }
        }
    };

    // prologue: rows h0-1, h0, h0+1 staged; loads for h0+2 left in flight
    issue_loads(h0 - 1); write_stage(h0 - 1);
    issue_loads(h0);     write_stage(h0);
    issue_loads(h0 + 1); write_stage(h0 + 1);
    issue_loads(h0 + 2);
    asm volatile("s_waitcnt lgkmcnt(0)" ::: "memory");
    __builtin_amdgcn_s_barrier();

    // A-frags from LDS W (once): lane l -> e = e0+l31, c = lhalf*8..+8
    bf16x8 afrag[9];
    #pragma unroll
    for (int tap = 0; tap < 9; ++tap)
        afrag[tap] = *reinterpret_cast<const bf16x8*>(WB + tap * 1024 + l31 * 32 + lhalf * 16);

    float bb[4];
    #pragma unroll
    for (int i = 0; i < 4; ++i) bb[i] = bias[e0 + wid * 4 + i];

    for (int h = h0; h < h0 + 16; ++h) {
        // write row h+2 (loads issued last iter), then issue loads for h+3
        if (h + 2 <= h0 + 16) write_stage(h + 2);
        if (h + 3 <= h0 + 16) issue_loads(h + 3);
        asm volatile("s_waitcnt lgkmcnt(0)" ::: "memory");
        __builtin_amdgcn_s_barrier();

        f32x16 acc;
        #pragma unroll
        for (int r = 0; r < 16; ++r) acc[r] = 0.f;

        #pragma unroll
        for (int kh = 0; kh < 3; ++kh) {
            const char* base = XB + ((h + kh) & 3) * SLOT_BYTES;  // slot(ir=h-1+kh)
            #pragma unroll
            for (int kw = 0; kw < 3; ++kw) {
                const int wp = w0 + l31 + kw;
                bf16x8 bfrag = *reinterpret_cast<const bf16x8*>(base + xswz(wp, lhalf << 4));
                acc = __builtin_amdgcn_mfma_f32_32x32x16_bf16(afrag[kh * 3 + kw], bfrag, acc, 0, 0, 0);
            }
        }

        // epilogue scatter (LDS), then coalesced 1KB-row nt stores
        #pragma unroll
        for (int r = 0; r < 16; ++r) {
            const int erow = (r & 3) + 8 * (r >> 2) + 4 * lhalf;
            EPI[erow * 256 + w0 + l31] = acc[r];
        }
        asm volatile("s_waitcnt lgkmcnt(0)" ::: "memory");
        __builtin_amdgcn_s_barrier();

        #pragma unroll
        for (int i = 0; i < 4; ++i) {
            const int e = wid * 4 + i;
            f32x4 v = *reinterpret_cast<const f32x4*>(&EPI[e * 256 + lane * 4]);
            v += bb[i];
            __builtin_nontemporal_store(v,
                reinterpret_cast<f32x4*>(&out[((size_t)(b * EE + e0 + e) * HH + h) * WW + lane * 4]));
        }
    }
}

extern "C" void kernel_launch(void* const* d_in, const int* in_sizes, int n_in,
                              void* d_out, int out_size, void* d_ws, size_t ws_size,
                              hipStream_t stream) {
    const float* x       = (const float*)d_in[0];
    const int*   indices = (const int*)  d_in[1];
    const float* emb     = (const float*)d_in[2];
    const float* bias    = (const float*)d_in[3];
    float*       out     = (float*)d_out;

    conv_fused<<<dim3(BB, 16, 8), dim3(512), 0, stream>>>(x, indices, emb, bias, out);
}